// Round 8
// baseline (140.063 us; speedup 1.0000x reference)
//
#include <hip/hip_runtime.h>
#include <hip/hip_fp16.h>

#define N_NEURON 500000
#define N_EDGE   10000000

// DT=0.1, TAO_D=2.0, TAO_R=10.0
#define DT_C      0.1f
#define LAMDA_D_C 0.05f
#define LAMDA_R_C 0.01f
#define INV_TAO_D 0.5f

// ---- binning geometry ----
#define BUCKET_SHIFT 11
#define BUCKET_W     (1 << BUCKET_SHIFT)                          // 2048
#define NBUCKET      ((N_NEURON + BUCKET_W - 1) >> BUCKET_SHIFT)  // 245

#define P1_BLOCK 512
#define P1_EPT   32
#define P1_CHUNK (P1_BLOCK * P1_EPT)                    // 16384 edges/block
#define NCHUNK   ((N_EDGE + P1_CHUNK - 1) / P1_CHUNK)   // 611
#define OFFS_STRIDE 256                                 // offs row stride (u32)

// ws layout: r_new | offs | records
#define WS_RNEW_OFF  0u
#define WS_OFFS_OFF  (2u * 1024u * 1024u)
#define WS_REC_OFF   (4u * 1024u * 1024u)
#define WS_NEEDED    ((size_t)WS_REC_OFF + (size_t)NCHUNK * P1_CHUNK * 4u)  // ~44 MB

// record = (fp16(value) << 16) | (post & 2047)
__device__ __forceinline__ unsigned pack_rec(int post, float v) {
    const unsigned short hv = __half_as_ushort(__float2half_rn(v));
    return ((unsigned)hv << 16) | ((unsigned)post & (BUCKET_W - 1));
}
__device__ __forceinline__ float rec_val(unsigned rec) {
    return __half2float(__ushort_as_half((unsigned short)(rec >> 16)));
}

// Kernel 1: r_new only (Ieff fused into bucket_reduce epilogue).
__global__ void neuron_update_r(const float4* __restrict__ spike,
                                const float4* __restrict__ s,
                                const float4* __restrict__ r,
                                float4* __restrict__ r_new,
                                int n4) {
    const int i = blockIdx.x * blockDim.x + threadIdx.x;
    if (i >= n4) return;
    const float4 sv = s[i], sp = spike[i], rv = r[i];
    float4 rn;
    float sn;
    sn = sv.x + LAMDA_R_C * (-sv.x + sp.x * INV_TAO_D); rn.x = rv.x - LAMDA_D_C * rv.x + DT_C * sn;
    sn = sv.y + LAMDA_R_C * (-sv.y + sp.y * INV_TAO_D); rn.y = rv.y - LAMDA_D_C * rv.y + DT_C * sn;
    sn = sv.z + LAMDA_R_C * (-sv.z + sp.z * INV_TAO_D); rn.z = rv.z - LAMDA_D_C * rv.z + DT_C * sn;
    sn = sv.w + LAMDA_R_C * (-sv.w + sp.w * INV_TAO_D); rn.w = rv.w - LAMDA_D_C * rv.w + DT_C * sn;
    r_new[i] = rn;
}

// Pass 1: block-local counting sort of 16384 edges, deep-ILP version.
// Phase A: staged int4 preloads -> fire-and-forget histogram atomics.
// Phase C: staged (post,pre,w) preloads -> 16 independent gathers ->
//          rank atomic + ranked LDS write. One contiguous flush per block.
__global__ __launch_bounds__(P1_BLOCK, 4) void edge_bin(
        const float* __restrict__ weight,
        const int*   __restrict__ post_arr,
        const int*   __restrict__ pre_arr,
        const float* __restrict__ r_new,
        unsigned*    __restrict__ records,
        unsigned*    __restrict__ offs,
        int n_edge) {
    __shared__ unsigned rec_lds[P1_CHUNK];
    __shared__ unsigned cnt[NBUCKET];
    __shared__ unsigned lbase[NBUCKET + 1];  // exclusive scan; [NBUCKET]=total

    const int t      = threadIdx.x;
    const int chunk0 = blockIdx.x * P1_CHUNK;

    for (int i = t; i < NBUCKET; i += P1_BLOCK) cnt[i] = 0;
    __syncthreads();

    // Phase A: histogram. Stage all 8 int4 loads, then 32 atomics (no return).
    {
        int4 P[8];
        #pragma unroll
        for (int k = 0; k < 8; ++k) {
            const int e = chunk0 + (k * P1_BLOCK + t) * 4;
            P[k] = (e < n_edge) ? *reinterpret_cast<const int4*>(post_arr + e)
                                : make_int4(-1, -1, -1, -1);
        }
        #pragma unroll
        for (int k = 0; k < 8; ++k) {
            if (P[k].x >= 0) {
                atomicAdd(&cnt[((unsigned)P[k].x) >> BUCKET_SHIFT], 1u);
                atomicAdd(&cnt[((unsigned)P[k].y) >> BUCKET_SHIFT], 1u);
                atomicAdd(&cnt[((unsigned)P[k].z) >> BUCKET_SHIFT], 1u);
                atomicAdd(&cnt[((unsigned)P[k].w) >> BUCKET_SHIFT], 1u);
            }
        }
    }
    __syncthreads();

    // Wave-0 exclusive scan of cnt -> lbase[0..245]
    if (t < 64) {
        unsigned carry = 0;
        #pragma unroll
        for (int c = 0; c < 4; ++c) {
            const int idx = c * 64 + t;
            unsigned v = (idx < NBUCKET) ? cnt[idx] : 0u;
            const unsigned orig = v;
            #pragma unroll
            for (int d = 1; d < 64; d <<= 1) {
                const unsigned u = __shfl_up(v, d);
                if (t >= d) v += u;
            }
            if (idx <= NBUCKET) lbase[idx] = carry + v - orig;
            carry += __shfl(v, 63);
        }
    }
    __syncthreads();

    // reset cnt for reuse as fill counters
    for (int i = t; i < NBUCKET; i += P1_BLOCK) cnt[i] = 0;
    __syncthreads();

    // Phase C: two half-passes of 16 edges; stage loads, then gathers, then
    // rank+scatter. All VMEM within a half-pass is independent (deep pipeline).
    #pragma unroll
    for (int h = 0; h < 2; ++h) {
        int4   P[4], Q[4];
        float4 W[4];
        #pragma unroll
        for (int k = 0; k < 4; ++k) {
            const int e = chunk0 + ((h * 4 + k) * P1_BLOCK + t) * 4;
            if (e < n_edge) {
                P[k] = *reinterpret_cast<const int4*>(post_arr + e);
                Q[k] = *reinterpret_cast<const int4*>(pre_arr + e);
                W[k] = *reinterpret_cast<const float4*>(weight + e);
            } else {
                P[k] = make_int4(-1, -1, -1, -1);
                Q[k] = make_int4(0, 0, 0, 0);
                W[k] = make_float4(0.f, 0.f, 0.f, 0.f);
            }
        }
        float g[16];
        #pragma unroll
        for (int k = 0; k < 4; ++k) {
            g[k * 4 + 0] = r_new[Q[k].x];
            g[k * 4 + 1] = r_new[Q[k].y];
            g[k * 4 + 2] = r_new[Q[k].z];
            g[k * 4 + 3] = r_new[Q[k].w];
        }
        #pragma unroll
        for (int k = 0; k < 4; ++k) {
            const int   ps[4] = {P[k].x, P[k].y, P[k].z, P[k].w};
            const float wv[4] = {W[k].x, W[k].y, W[k].z, W[k].w};
            #pragma unroll
            for (int j = 0; j < 4; ++j) {
                if (ps[j] >= 0) {
                    const unsigned b = ((unsigned)ps[j]) >> BUCKET_SHIFT;
                    const unsigned l = atomicAdd(&cnt[b], 1u);
                    rec_lds[lbase[b] + l] = pack_rec(ps[j], wv[j] * g[k * 4 + j]);
                }
            }
        }
    }
    __syncthreads();

    // Phase D: offset table + fully-coalesced contiguous flush
    if (t <= NBUCKET)
        offs[blockIdx.x * OFFS_STRIDE + t] = lbase[t];
    const unsigned total = lbase[NBUCKET];
    unsigned* dst = records + (size_t)blockIdx.x * P1_CHUNK;
    for (unsigned i = t; i < total; i += P1_BLOCK)
        dst[i] = rec_lds[i];
}

// Pass 2: block b = bucket b. 32 lane-groups of 32 gather per-region runs,
// accumulate into LDS; epilogue computes Ieff inline: out = acc + Ieff.
__global__ __launch_bounds__(1024) void bucket_reduce(
        const unsigned* __restrict__ records,
        const unsigned* __restrict__ offs,
        const float* __restrict__ Iback,
        const float* __restrict__ noise,
        const float* __restrict__ dt_over_tau,
        const float* __restrict__ sqrt_coeff,
        const float* __restrict__ sig,
        const float* __restrict__ mu,
        float*          __restrict__ out,
        int n, int nchunk) {
    __shared__ float acc[BUCKET_W];
    const int b = blockIdx.x;
    const int t = threadIdx.x;
    for (int i = t; i < BUCKET_W; i += 1024) acc[i] = 0.f;
    __syncthreads();

    const int grp = t >> 5, lane = t & 31;   // 32 groups x 32 lanes
    for (int j = grp; j < nchunk; j += 32) {
        const unsigned s0 = offs[j * OFFS_STRIDE + b];
        const unsigned e0 = offs[j * OFFS_STRIDE + b + 1];
        const unsigned* src = records + (size_t)j * P1_CHUNK;
        for (unsigned i = s0 + lane; i < e0; i += 32) {
            const unsigned rec = src[i];
            atomicAdd(&acc[rec & (BUCKET_W - 1)], rec_val(rec));
        }
    }
    __syncthreads();

    const float dtau = dt_over_tau[0];
    const float sq   = sqrt_coeff[0];
    const float sg   = sig[0];
    const float m    = mu[0];
    const int g0 = b << BUCKET_SHIFT;
    for (int i = t; i < BUCKET_W; i += 1024) {
        const int g = g0 + i;
        if (g < n) {
            const float ib  = Iback[g];
            const float ibn = ib + dtau * (noise[g] - ib);
            out[g] = acc[i] + (ibn / sq * sg + m);
        }
    }
}

// ---- fallback path (ws too small): full neuron update + naive scatter ----
__global__ void neuron_update_full(const float* __restrict__ Iback,
                                   const float* __restrict__ spike,
                                   const float* __restrict__ s,
                                   const float* __restrict__ r,
                                   const float* __restrict__ noise,
                                   const float* __restrict__ dt_over_tau,
                                   const float* __restrict__ sqrt_coeff,
                                   const float* __restrict__ sig,
                                   const float* __restrict__ mu,
                                   float* __restrict__ r_new,
                                   float* __restrict__ out,
                                   int n) {
    const float dtau = dt_over_tau[0], sq = sqrt_coeff[0], sg = sig[0], m = mu[0];
    for (int i = blockIdx.x * blockDim.x + threadIdx.x; i < n;
         i += gridDim.x * blockDim.x) {
        float ib  = Iback[i];
        float ibn = ib + dtau * (noise[i] - ib);
        float sv  = s[i];
        float sn  = sv + LAMDA_R_C * (-sv + spike[i] * INV_TAO_D);
        float rv  = r[i];
        r_new[i] = rv - LAMDA_D_C * rv + DT_C * sn;
        out[i]   = ibn / sq * sg + m;
    }
}

__global__ void edge_scatter(const float* __restrict__ weight,
                             const int* __restrict__ post,
                             const int* __restrict__ pre,
                             const float* __restrict__ r_new,
                             float* __restrict__ out,
                             int n_edge) {
    for (int e = blockIdx.x * blockDim.x + threadIdx.x; e < n_edge;
         e += gridDim.x * blockDim.x) {
        atomicAdd(&out[post[e]], weight[e] * r_new[pre[e]]);
    }
}

extern "C" void kernel_launch(void* const* d_in, const int* in_sizes, int n_in,
                              void* d_out, int out_size, void* d_ws, size_t ws_size,
                              hipStream_t stream) {
    const float* weight      = (const float*)d_in[0];
    const int*   edges       = (const int*)d_in[1];   // (2, N_EDGE): post then pre
    const float* Iback       = (const float*)d_in[2];
    const float* spike       = (const float*)d_in[3];
    const float* s           = (const float*)d_in[4];
    const float* r           = (const float*)d_in[5];
    const float* noise       = (const float*)d_in[6];
    const float* dt_over_tau = (const float*)d_in[7];
    const float* sqrt_coeff  = (const float*)d_in[8];
    const float* sig         = (const float*)d_in[9];
    const float* mu          = (const float*)d_in[10];

    float* out = (float*)d_out;
    char*  ws  = (char*)d_ws;

    float*    r_new   = (float*)(ws + WS_RNEW_OFF);
    unsigned* offs    = (unsigned*)(ws + WS_OFFS_OFF);
    unsigned* records = (unsigned*)(ws + WS_REC_OFF);

    const int n_edge = in_sizes[0];   // 10M
    const int n      = out_size;      // 500k (multiple of 4)

    const int nchunk = (n_edge + P1_CHUNK - 1) / P1_CHUNK;  // 611

    if (ws_size >= WS_NEEDED) {
        // 1) r_new only (Ieff fused into pass 2)
        {
            const int n4 = n / 4;
            neuron_update_r<<<(n4 + 255) / 256, 256, 0, stream>>>(
                (const float4*)spike, (const float4*)s, (const float4*)r,
                (float4*)r_new, n4);
        }
        // 2) deep-ILP counting sort -> block-contiguous packed runs
        edge_bin<<<nchunk, P1_BLOCK, 0, stream>>>(
            weight, edges, edges + n_edge, r_new, records, offs, n_edge);

        // 3) per-bucket gather + LDS reduce + fused Ieff -> out
        bucket_reduce<<<NBUCKET, 1024, 0, stream>>>(
            records, offs, Iback, noise, dt_over_tau, sqrt_coeff, sig, mu,
            out, n, nchunk);
    } else {
        neuron_update_full<<<(n + 255) / 256, 256, 0, stream>>>(
            Iback, spike, s, r, noise, dt_over_tau, sqrt_coeff, sig, mu,
            r_new, out, n);
        edge_scatter<<<4096, 256, 0, stream>>>(
            weight, edges, edges + n_edge, r_new, out, n_edge);
    }
}

// Round 9
// 125.594 us; speedup vs baseline: 1.1152x; 1.1152x over previous
//
#include <hip/hip_runtime.h>
#include <hip/hip_fp16.h>

#define N_NEURON 500000
#define N_EDGE   10000000

// DT=0.1, TAO_D=2.0, TAO_R=10.0
#define DT_C      0.1f
#define LAMDA_D_C 0.05f
#define LAMDA_R_C 0.01f
#define INV_TAO_D 0.5f

// ---- binning geometry ----
#define BUCKET_SHIFT 11
#define BUCKET_W     (1 << BUCKET_SHIFT)                          // 2048
#define NBUCKET      ((N_NEURON + BUCKET_W - 1) >> BUCKET_SHIFT)  // 245

#define P1_BLOCK 256
#define P1_EPT   16
#define P1_CHUNK (P1_BLOCK * P1_EPT)                    // 4096 edges/block
#define NCHUNK   ((N_EDGE + P1_CHUNK - 1) / P1_CHUNK)   // 2442
#define OFFS_STRIDE 256                                 // offs row stride (u32)

// ws layout: r_new | offs | records
#define WS_RNEW_OFF  0u
#define WS_OFFS_OFF  (2u * 1024u * 1024u)
#define WS_REC_OFF   (8u * 1024u * 1024u)               // offs needs 2.5 MB
#define WS_NEEDED    ((size_t)WS_REC_OFF + (size_t)NCHUNK * P1_CHUNK * 4u)  // ~48 MB

// record = (fp16(value) << 16) | (post & 2047)
__device__ __forceinline__ unsigned pack_rec(int post, float v) {
    const unsigned short hv = __half_as_ushort(__float2half_rn(v));
    return ((unsigned)hv << 16) | ((unsigned)post & (BUCKET_W - 1));
}
__device__ __forceinline__ float rec_val(unsigned rec) {
    return __half2float(__ushort_as_half((unsigned short)(rec >> 16)));
}

// Kernel 1: r_new only (Ieff fused into bucket_reduce epilogue).
__global__ void neuron_update_r(const float4* __restrict__ spike,
                                const float4* __restrict__ s,
                                const float4* __restrict__ r,
                                float4* __restrict__ r_new,
                                int n4) {
    const int i = blockIdx.x * blockDim.x + threadIdx.x;
    if (i >= n4) return;
    const float4 sv = s[i], sp = spike[i], rv = r[i];
    float4 rn;
    float sn;
    sn = sv.x + LAMDA_R_C * (-sv.x + sp.x * INV_TAO_D); rn.x = rv.x - LAMDA_D_C * rv.x + DT_C * sn;
    sn = sv.y + LAMDA_R_C * (-sv.y + sp.y * INV_TAO_D); rn.y = rv.y - LAMDA_D_C * rv.y + DT_C * sn;
    sn = sv.z + LAMDA_R_C * (-sv.z + sp.z * INV_TAO_D); rn.z = rv.z - LAMDA_D_C * rv.z + DT_C * sn;
    sn = sv.w + LAMDA_R_C * (-sv.w + sp.w * INV_TAO_D); rn.w = rv.w - LAMDA_D_C * rv.w + DT_C * sn;
    r_new[i] = rn;
}

// Pass 1: block-local counting sort of 4096 edges. Small LDS (~19 KB) so 8
// blocks/CU co-reside (32 waves). Rank atomics return ABSOLUTE slots
// (lfill pre-loaded with scanned bases): no reset pass, 4 barriers total.
__global__ __launch_bounds__(P1_BLOCK, 8) void edge_bin(
        const float* __restrict__ weight,
        const int*   __restrict__ post_arr,
        const int*   __restrict__ pre_arr,
        const float* __restrict__ r_new,
        unsigned*    __restrict__ records,
        unsigned*    __restrict__ offs,
        int n_edge) {
    __shared__ unsigned rec_lds[P1_CHUNK];
    __shared__ unsigned cnt[NBUCKET];
    __shared__ unsigned lbase[NBUCKET + 1];  // scan result (kept intact)
    __shared__ unsigned lfill[NBUCKET];      // scan result (consumed by ranks)

    const int t      = threadIdx.x;
    const int chunk0 = blockIdx.x * P1_CHUNK;

    for (int i = t; i < NBUCKET; i += P1_BLOCK) cnt[i] = 0;
    __syncthreads();

    // Phase A: histogram. Stage 4 int4 loads, then 16 fire-and-forget atomics.
    {
        int4 P[4];
        #pragma unroll
        for (int k = 0; k < 4; ++k) {
            const int e = chunk0 + (k * P1_BLOCK + t) * 4;
            P[k] = (e < n_edge) ? *reinterpret_cast<const int4*>(post_arr + e)
                                : make_int4(-1, -1, -1, -1);
        }
        #pragma unroll
        for (int k = 0; k < 4; ++k) {
            if (P[k].x >= 0) {
                atomicAdd(&cnt[((unsigned)P[k].x) >> BUCKET_SHIFT], 1u);
                atomicAdd(&cnt[((unsigned)P[k].y) >> BUCKET_SHIFT], 1u);
                atomicAdd(&cnt[((unsigned)P[k].z) >> BUCKET_SHIFT], 1u);
                atomicAdd(&cnt[((unsigned)P[k].w) >> BUCKET_SHIFT], 1u);
            }
        }
    }
    __syncthreads();

    // Wave-0 exclusive scan of cnt -> lbase[0..245] and lfill[0..244]
    if (t < 64) {
        unsigned carry = 0;
        #pragma unroll
        for (int c = 0; c < 4; ++c) {
            const int idx = c * 64 + t;
            unsigned v = (idx < NBUCKET) ? cnt[idx] : 0u;
            const unsigned orig = v;
            #pragma unroll
            for (int d = 1; d < 64; d <<= 1) {
                const unsigned u = __shfl_up(v, d);
                if (t >= d) v += u;
            }
            if (idx <= NBUCKET) {
                const unsigned ex = carry + v - orig;
                lbase[idx] = ex;
                if (idx < NBUCKET) lfill[idx] = ex;
            }
            carry += __shfl(v, 63);
        }
    }
    __syncthreads();

    // offs table (reads lbase; ranks consume lfill, so no race)
    if (t <= NBUCKET)
        offs[blockIdx.x * OFFS_STRIDE + t] = lbase[t];

    // Phase C: two half-batches of 8 edges. Stage loads -> 8 gathers ->
    // 8 rank atomics (absolute slot) -> 8 LDS writes. Batched issue.
    #pragma unroll
    for (int h = 0; h < 2; ++h) {
        int4   P[2], Q[2];
        float4 W[2];
        #pragma unroll
        for (int k = 0; k < 2; ++k) {
            const int e = chunk0 + ((h * 2 + k) * P1_BLOCK + t) * 4;
            if (e < n_edge) {
                P[k] = *reinterpret_cast<const int4*>(post_arr + e);
                Q[k] = *reinterpret_cast<const int4*>(pre_arr + e);
                W[k] = *reinterpret_cast<const float4*>(weight + e);
            } else {
                P[k] = make_int4(-1, -1, -1, -1);
                Q[k] = make_int4(0, 0, 0, 0);
                W[k] = make_float4(0.f, 0.f, 0.f, 0.f);
            }
        }
        float g[8];
        #pragma unroll
        for (int k = 0; k < 2; ++k) {
            g[k * 4 + 0] = r_new[Q[k].x];
            g[k * 4 + 1] = r_new[Q[k].y];
            g[k * 4 + 2] = r_new[Q[k].z];
            g[k * 4 + 3] = r_new[Q[k].w];
        }
        unsigned slot[8], rec[8];
        #pragma unroll
        for (int k = 0; k < 2; ++k) {
            const int   ps[4] = {P[k].x, P[k].y, P[k].z, P[k].w};
            const float wv[4] = {W[k].x, W[k].y, W[k].z, W[k].w};
            #pragma unroll
            for (int j = 0; j < 4; ++j) {
                const int m = k * 4 + j;
                if (ps[j] >= 0) {
                    slot[m] = atomicAdd(&lfill[((unsigned)ps[j]) >> BUCKET_SHIFT], 1u);
                    rec[m]  = pack_rec(ps[j], wv[j] * g[m]);
                } else {
                    slot[m] = 0xFFFFFFFFu;
                }
            }
        }
        #pragma unroll
        for (int m = 0; m < 8; ++m)
            if (slot[m] != 0xFFFFFFFFu) rec_lds[slot[m]] = rec[m];
    }
    __syncthreads();

    // Phase D: fully-coalesced contiguous flush
    const unsigned total = lbase[NBUCKET];
    unsigned* dst = records + (size_t)blockIdx.x * P1_CHUNK;
    for (unsigned i = t; i < total; i += P1_BLOCK)
        dst[i] = rec_lds[i];
}

// Pass 2: block b = bucket b. 64 lane-groups of 16 gather per-region runs
// (avg run ~17), accumulate into LDS; epilogue fuses Ieff: out = acc + Ieff.
__global__ __launch_bounds__(1024) void bucket_reduce(
        const unsigned* __restrict__ records,
        const unsigned* __restrict__ offs,
        const float* __restrict__ Iback,
        const float* __restrict__ noise,
        const float* __restrict__ dt_over_tau,
        const float* __restrict__ sqrt_coeff,
        const float* __restrict__ sig,
        const float* __restrict__ mu,
        float*          __restrict__ out,
        int n, int nchunk) {
    __shared__ float acc[BUCKET_W];
    const int b = blockIdx.x;
    const int t = threadIdx.x;
    for (int i = t; i < BUCKET_W; i += 1024) acc[i] = 0.f;
    __syncthreads();

    const int grp = t >> 4, lane = t & 15;   // 64 groups x 16 lanes
    for (int j = grp; j < nchunk; j += 64) {
        const unsigned s0 = offs[j * OFFS_STRIDE + b];
        const unsigned e0 = offs[j * OFFS_STRIDE + b + 1];
        const unsigned* src = records + (size_t)j * P1_CHUNK;
        for (unsigned i = s0 + lane; i < e0; i += 16) {
            const unsigned rec = src[i];
            atomicAdd(&acc[rec & (BUCKET_W - 1)], rec_val(rec));
        }
    }
    __syncthreads();

    const float dtau = dt_over_tau[0];
    const float sq   = sqrt_coeff[0];
    const float sg   = sig[0];
    const float m    = mu[0];
    const int g0 = b << BUCKET_SHIFT;
    for (int i = t; i < BUCKET_W; i += 1024) {
        const int g = g0 + i;
        if (g < n) {
            const float ib  = Iback[g];
            const float ibn = ib + dtau * (noise[g] - ib);
            out[g] = acc[i] + (ibn / sq * sg + m);
        }
    }
}

// ---- fallback path (ws too small): full neuron update + naive scatter ----
__global__ void neuron_update_full(const float* __restrict__ Iback,
                                   const float* __restrict__ spike,
                                   const float* __restrict__ s,
                                   const float* __restrict__ r,
                                   const float* __restrict__ noise,
                                   const float* __restrict__ dt_over_tau,
                                   const float* __restrict__ sqrt_coeff,
                                   const float* __restrict__ sig,
                                   const float* __restrict__ mu,
                                   float* __restrict__ r_new,
                                   float* __restrict__ out,
                                   int n) {
    const float dtau = dt_over_tau[0], sq = sqrt_coeff[0], sg = sig[0], m = mu[0];
    for (int i = blockIdx.x * blockDim.x + threadIdx.x; i < n;
         i += gridDim.x * blockDim.x) {
        float ib  = Iback[i];
        float ibn = ib + dtau * (noise[i] - ib);
        float sv  = s[i];
        float sn  = sv + LAMDA_R_C * (-sv + spike[i] * INV_TAO_D);
        float rv  = r[i];
        r_new[i] = rv - LAMDA_D_C * rv + DT_C * sn;
        out[i]   = ibn / sq * sg + m;
    }
}

__global__ void edge_scatter(const float* __restrict__ weight,
                             const int* __restrict__ post,
                             const int* __restrict__ pre,
                             const float* __restrict__ r_new,
                             float* __restrict__ out,
                             int n_edge) {
    for (int e = blockIdx.x * blockDim.x + threadIdx.x; e < n_edge;
         e += gridDim.x * blockDim.x) {
        atomicAdd(&out[post[e]], weight[e] * r_new[pre[e]]);
    }
}

extern "C" void kernel_launch(void* const* d_in, const int* in_sizes, int n_in,
                              void* d_out, int out_size, void* d_ws, size_t ws_size,
                              hipStream_t stream) {
    const float* weight      = (const float*)d_in[0];
    const int*   edges       = (const int*)d_in[1];   // (2, N_EDGE): post then pre
    const float* Iback       = (const float*)d_in[2];
    const float* spike       = (const float*)d_in[3];
    const float* s           = (const float*)d_in[4];
    const float* r           = (const float*)d_in[5];
    const float* noise       = (const float*)d_in[6];
    const float* dt_over_tau = (const float*)d_in[7];
    const float* sqrt_coeff  = (const float*)d_in[8];
    const float* sig         = (const float*)d_in[9];
    const float* mu          = (const float*)d_in[10];

    float* out = (float*)d_out;
    char*  ws  = (char*)d_ws;

    float*    r_new   = (float*)(ws + WS_RNEW_OFF);
    unsigned* offs    = (unsigned*)(ws + WS_OFFS_OFF);
    unsigned* records = (unsigned*)(ws + WS_REC_OFF);

    const int n_edge = in_sizes[0];   // 10M
    const int n      = out_size;      // 500k (multiple of 4)

    const int nchunk = (n_edge + P1_CHUNK - 1) / P1_CHUNK;  // 2442

    if (ws_size >= WS_NEEDED) {
        // 1) r_new only (Ieff fused into pass 2)
        {
            const int n4 = n / 4;
            neuron_update_r<<<(n4 + 255) / 256, 256, 0, stream>>>(
                (const float4*)spike, (const float4*)s, (const float4*)r,
                (float4*)r_new, n4);
        }
        // 2) high-residency counting sort -> block-contiguous packed runs
        edge_bin<<<nchunk, P1_BLOCK, 0, stream>>>(
            weight, edges, edges + n_edge, r_new, records, offs, n_edge);

        // 3) per-bucket gather + LDS reduce + fused Ieff -> out
        bucket_reduce<<<NBUCKET, 1024, 0, stream>>>(
            records, offs, Iback, noise, dt_over_tau, sqrt_coeff, sig, mu,
            out, n, nchunk);
    } else {
        neuron_update_full<<<(n + 255) / 256, 256, 0, stream>>>(
            Iback, spike, s, r, noise, dt_over_tau, sqrt_coeff, sig, mu,
            r_new, out, n);
        edge_scatter<<<4096, 256, 0, stream>>>(
            weight, edges, edges + n_edge, r_new, out, n_edge);
    }
}